// Round 1
// baseline (585.911 us; speedup 1.0000x reference)
//
#include <hip/hip_runtime.h>

#define N_NODES 65536
#define N_EDGES 1048576
#define DIM 64
#define M_POOL (N_NODES / DIM)  // 1024

// ---------------- degree / norm precompute ----------------

__global__ __launch_bounds__(256) void init_deg(float* __restrict__ deg) {
    int i = blockIdx.x * 256 + threadIdx.x;
    if (i < N_NODES) deg[i] = 1.0f;  // self-loop weight
}

__global__ __launch_bounds__(256) void accum_deg(const int* __restrict__ col,
                                                 const float* __restrict__ ew,
                                                 float* __restrict__ deg) {
    int e = blockIdx.x * 256 + threadIdx.x;
    int stride = gridDim.x * 256;
    for (; e < N_EDGES; e += stride) atomicAdd(&deg[col[e]], ew[e]);
}

__global__ __launch_bounds__(256) void finalize_dinv(float* __restrict__ deg) {
    int i = blockIdx.x * 256 + threadIdx.x;
    if (i < N_NODES) deg[i] = 1.0f / sqrtf(deg[i]);  // deg >= 1 always
}

__global__ __launch_bounds__(256) void compute_norm(const int* __restrict__ row,
                                                    const int* __restrict__ col,
                                                    const float* __restrict__ ew,
                                                    const float* __restrict__ dinv,
                                                    float* __restrict__ norm) {
    int e = blockIdx.x * 256 + threadIdx.x;
    int stride = gridDim.x * 256;
    for (; e < N_EDGES; e += stride)
        norm[e] = dinv[row[e]] * ew[e] * dinv[col[e]];
}

// ---------------- GEMM (x @ W) + fused self-loop/bias init of agg ----------
// h[i][:]   = xin[i][:] @ W
// agg[i][:] = h[i][:] * dinv[i]^2 + b[:]
// xin MAY alias agg (layer 2 runs in-place): each block stages its 16 rows in
// LDS before writing, and owns those rows exclusively for read+write.

__global__ __launch_bounds__(256) void gemm_agginit(const float* __restrict__ xin,
                                                    const float* __restrict__ W,
                                                    const float* __restrict__ b,
                                                    const float* __restrict__ dinv,
                                                    float* __restrict__ h,
                                                    float* __restrict__ agg) {
    __shared__ float Ws[DIM * DIM];   // 16 KiB
    __shared__ float Xs[16][DIM];     // 4 KiB
    const int tid = threadIdx.x;
    const int row0 = blockIdx.x * 16;

    for (int i = tid; i < DIM * DIM; i += 256) Ws[i] = W[i];
    for (int i = tid; i < 16 * DIM; i += 256)
        Xs[i >> 6][i & 63] = xin[(row0 + (i >> 6)) * DIM + (i & 63)];
    __syncthreads();

    const int j = tid & 63;       // output column
    const int rs = tid >> 6;      // 0..3 -> rows rs*4 .. rs*4+3
    const float bj = b[j];
    for (int rr = 0; rr < 4; ++rr) {
        const int r = rs * 4 + rr;
        float acc = 0.f;
#pragma unroll
        for (int k = 0; k < DIM; ++k) acc += Xs[r][k] * Ws[k * DIM + j];
        const int gi = row0 + r;
        const float dv = dinv[gi];
        h[gi * DIM + j] = acc;
        agg[gi * DIM + j] = acc * dv * dv + bj;
    }
}

// ---------------- edge scatter: agg[col] += norm * h[row] -------------------
// one wave (64 lanes) per edge; lane == feature dim

__global__ __launch_bounds__(256) void scatter_edges(const int* __restrict__ row,
                                                     const int* __restrict__ col,
                                                     const float* __restrict__ norm,
                                                     const float* __restrict__ h,
                                                     float* __restrict__ agg) {
    const int lane = threadIdx.x & 63;
    const int wave = (blockIdx.x * 256 + threadIdx.x) >> 6;
    const int nwaves = (gridDim.x * 256) >> 6;
    for (int e = wave; e < N_EDGES; e += nwaves) {
        const int r = row[e];
        const int c = col[e];
        const float nv = norm[e];
        const float v = nv * h[r * DIM + lane];
        atomicAdd(&agg[c * DIM + lane], v);
    }
}

// ---------------- pooling: out[d][m] = mean_w agg[(m*64+w)][d] --------------

__global__ __launch_bounds__(256) void pool_kernel(const float* __restrict__ agg,
                                                   float* __restrict__ out) {
    const int tid = threadIdx.x;
    const int d = tid & 63;
    const int m = blockIdx.x * 4 + (tid >> 6);
    float acc = 0.f;
#pragma unroll 8
    for (int w = 0; w < DIM; ++w) acc += agg[(m * DIM + w) * DIM + d];
    out[d * M_POOL + m] = acc * (1.0f / DIM);
}

// ---------------- launcher --------------------------------------------------

extern "C" void kernel_launch(void* const* d_in, const int* in_sizes, int n_in,
                              void* d_out, int out_size, void* d_ws, size_t ws_size,
                              hipStream_t stream) {
    const float* x  = (const float*)d_in[0];
    const int*   ei = (const int*)d_in[1];   // [2][E]
    const float* ew = (const float*)d_in[2];
    const float* W1 = (const float*)d_in[3];
    const float* b1 = (const float*)d_in[4];
    const float* W2 = (const float*)d_in[5];
    const float* b2 = (const float*)d_in[6];
    float* out = (float*)d_out;

    float* ws   = (float*)d_ws;
    float* dinv = ws;                       // N floats
    float* norm = dinv + N_NODES;           // E floats
    float* hbuf = norm + N_EDGES;           // N*D floats
    float* agg  = hbuf + N_NODES * DIM;     // N*D floats  (total ~36.3 MB)

    const int* row = ei;             // edge_index[0]
    const int* col = ei + N_EDGES;   // edge_index[1]

    init_deg<<<N_NODES / 256, 256, 0, stream>>>(dinv);
    accum_deg<<<2048, 256, 0, stream>>>(col, ew, dinv);
    finalize_dinv<<<N_NODES / 256, 256, 0, stream>>>(dinv);
    compute_norm<<<2048, 256, 0, stream>>>(row, col, ew, dinv, norm);

    // layer 1
    gemm_agginit<<<N_NODES / 16, 256, 0, stream>>>(x, W1, b1, dinv, hbuf, agg);
    scatter_edges<<<2048, 256, 0, stream>>>(row, col, norm, hbuf, agg);

    // layer 2 (in-place: agg is both GEMM input and agg-init output)
    gemm_agginit<<<N_NODES / 16, 256, 0, stream>>>(agg, W2, b2, dinv, hbuf, agg);
    scatter_edges<<<2048, 256, 0, stream>>>(row, col, norm, hbuf, agg);

    pool_kernel<<<M_POOL / 4, 256, 0, stream>>>(agg, out);
}

// Round 2
// 359.355 us; speedup vs baseline: 1.6305x; 1.6305x over previous
//
#include <hip/hip_runtime.h>

#define N_NODES 65536
#define N_EDGES 1048576
#define DIM 64
#define M_POOL (N_NODES / DIM)  // 1024

// ---------------- init: deg=1 (self-loop), cnt=0 ----------------

__global__ __launch_bounds__(256) void init_deg_cnt(float* __restrict__ deg,
                                                    int* __restrict__ cnt) {
    int i = blockIdx.x * 256 + threadIdx.x;
    if (i < N_NODES) { deg[i] = 1.0f; cnt[i] = 0; }
}

// ---------------- edge pass 1: weighted degree + in-degree histogram --------

__global__ __launch_bounds__(256) void edge_pass1(const int* __restrict__ col,
                                                  const float* __restrict__ ew,
                                                  float* __restrict__ deg,
                                                  int* __restrict__ cnt) {
    int e = blockIdx.x * 256 + threadIdx.x;
    int stride = gridDim.x * 256;
    for (; e < N_EDGES; e += stride) {
        int c = col[e];
        atomicAdd(&deg[c], ew[e]);
        atomicAdd(&cnt[c], 1);
    }
}

__global__ __launch_bounds__(256) void finalize_dinv(float* __restrict__ deg) {
    int i = blockIdx.x * 256 + threadIdx.x;
    if (i < N_NODES) deg[i] = 1.0f / sqrtf(deg[i]);  // deg >= 1 always
}

// ---------------- exclusive scan of cnt[65536] -> rowptr[65537] -------------
// single block, 1024 threads, 64 elements/thread

__global__ __launch_bounds__(1024) void scan_counts(const int* __restrict__ cnt,
                                                    int* __restrict__ rowptr) {
    __shared__ int part[1024];
    const int t = threadIdx.x;
    const int base = t * 64;
    int s = 0;
    for (int i = 0; i < 64; ++i) s += cnt[base + i];
    part[t] = s;
    __syncthreads();
    // Hillis-Steele inclusive scan
    for (int off = 1; off < 1024; off <<= 1) {
        int v = (t >= off) ? part[t - off] : 0;
        __syncthreads();
        part[t] += v;
        __syncthreads();
    }
    int offset = (t == 0) ? 0 : part[t - 1];
    for (int i = 0; i < 64; ++i) {
        rowptr[base + i] = offset;
        offset += cnt[base + i];
    }
    if (t == 1023) rowptr[N_NODES] = part[1023];
}

__global__ __launch_bounds__(256) void zero_cursor(int* __restrict__ cnt) {
    int i = blockIdx.x * 256 + threadIdx.x;
    if (i < N_NODES) cnt[i] = 0;
}

// ---------------- CSR fill (fused norm computation) -------------------------

__global__ __launch_bounds__(256) void csr_fill(const int* __restrict__ row,
                                                const int* __restrict__ col,
                                                const float* __restrict__ ew,
                                                const float* __restrict__ dinv,
                                                const int* __restrict__ rowptr,
                                                int* __restrict__ cursor,
                                                int* __restrict__ csr_src,
                                                float* __restrict__ csr_w) {
    int e = blockIdx.x * 256 + threadIdx.x;
    int stride = gridDim.x * 256;
    for (; e < N_EDGES; e += stride) {
        int r = row[e];
        int c = col[e];
        int p = atomicAdd(&cursor[c], 1);
        int idx = rowptr[c] + p;
        csr_src[idx] = r;
        csr_w[idx] = dinv[r] * ew[e] * dinv[c];
    }
}

// ---------------- GEMM: h = xin @ W ----------------------------------------

__global__ __launch_bounds__(256) void gemm64(const float* __restrict__ xin,
                                              const float* __restrict__ W,
                                              float* __restrict__ h) {
    __shared__ float Ws[DIM * DIM];   // 16 KiB
    __shared__ float Xs[16][DIM];     // 4 KiB
    const int tid = threadIdx.x;
    const int row0 = blockIdx.x * 16;

    for (int i = tid; i < DIM * DIM; i += 256) Ws[i] = W[i];
    for (int i = tid; i < 16 * DIM; i += 256)
        Xs[i >> 6][i & 63] = xin[(row0 + (i >> 6)) * DIM + (i & 63)];
    __syncthreads();

    const int j = tid & 63;       // output column
    const int rs = tid >> 6;      // 0..3
    for (int rr = 0; rr < 4; ++rr) {
        const int r = rs * 4 + rr;
        float acc = 0.f;
#pragma unroll
        for (int k = 0; k < DIM; ++k) acc += Xs[r][k] * Ws[k * DIM + j];
        h[(row0 + r) * DIM + j] = acc;
    }
}

// ---------------- aggregate: agg[c] = b + dinv[c]^2*h[c] + sum w*h[src] -----
// one wave per destination node, lane == feature dim, unroll 4 for MLP

__global__ __launch_bounds__(256) void aggregate_csr(const int* __restrict__ rowptr,
                                                     const int* __restrict__ csr_src,
                                                     const float* __restrict__ csr_w,
                                                     const float* __restrict__ h,
                                                     const float* __restrict__ dinv,
                                                     const float* __restrict__ b,
                                                     float* __restrict__ agg) {
    const int lane = threadIdx.x & 63;
    const int node = (blockIdx.x * 256 + threadIdx.x) >> 6;  // 4 nodes/block
    const int start = rowptr[node];
    const int end = rowptr[node + 1];
    const float dv = dinv[node];
    float acc = h[node * DIM + lane] * dv * dv + b[lane];

    int i = start;
    for (; i + 3 < end; i += 4) {
        const int s0 = csr_src[i + 0];
        const int s1 = csr_src[i + 1];
        const int s2 = csr_src[i + 2];
        const int s3 = csr_src[i + 3];
        const float w0 = csr_w[i + 0];
        const float w1 = csr_w[i + 1];
        const float w2 = csr_w[i + 2];
        const float w3 = csr_w[i + 3];
        const float h0 = h[s0 * DIM + lane];
        const float h1 = h[s1 * DIM + lane];
        const float h2 = h[s2 * DIM + lane];
        const float h3 = h[s3 * DIM + lane];
        acc += w0 * h0;
        acc += w1 * h1;
        acc += w2 * h2;
        acc += w3 * h3;
    }
    for (; i < end; ++i) acc += csr_w[i] * h[csr_src[i] * DIM + lane];

    agg[node * DIM + lane] = acc;
}

// ---------------- pooling: out[d][m] = mean_w agg[(m*64+w)][d] --------------

__global__ __launch_bounds__(256) void pool_kernel(const float* __restrict__ agg,
                                                   float* __restrict__ out) {
    const int tid = threadIdx.x;
    const int d = tid & 63;
    const int m = blockIdx.x * 4 + (tid >> 6);
    float acc = 0.f;
#pragma unroll 8
    for (int w = 0; w < DIM; ++w) acc += agg[(m * DIM + w) * DIM + d];
    out[d * M_POOL + m] = acc * (1.0f / DIM);
}

// ---------------- launcher --------------------------------------------------

extern "C" void kernel_launch(void* const* d_in, const int* in_sizes, int n_in,
                              void* d_out, int out_size, void* d_ws, size_t ws_size,
                              hipStream_t stream) {
    const float* x  = (const float*)d_in[0];
    const int*   ei = (const int*)d_in[1];   // [2][E]
    const float* ew = (const float*)d_in[2];
    const float* W1 = (const float*)d_in[3];
    const float* b1 = (const float*)d_in[4];
    const float* W2 = (const float*)d_in[5];
    const float* b2 = (const float*)d_in[6];
    float* out = (float*)d_out;

    char* w = (char*)d_ws;
    float* deg    = (float*)w; w += (size_t)N_NODES * 4;        // becomes dinv
    int*   cnt    = (int*)w;   w += (size_t)N_NODES * 4;        // also cursor
    int*   rowptr = (int*)w;   w += (size_t)(N_NODES + 16) * 4;
    int*   csr_src= (int*)w;   w += (size_t)N_EDGES * 4;
    float* csr_w  = (float*)w; w += (size_t)N_EDGES * 4;
    float* hbuf   = (float*)w; w += (size_t)N_NODES * DIM * 4;
    float* agg    = (float*)w;                                   // ~40.8 MB total

    const int* row = ei;             // edge_index[0]
    const int* col = ei + N_EDGES;   // edge_index[1]

    // graph preprocessing (shared by both layers)
    init_deg_cnt<<<N_NODES / 256, 256, 0, stream>>>(deg, cnt);
    edge_pass1<<<2048, 256, 0, stream>>>(col, ew, deg, cnt);
    finalize_dinv<<<N_NODES / 256, 256, 0, stream>>>(deg);
    scan_counts<<<1, 1024, 0, stream>>>(cnt, rowptr);
    zero_cursor<<<N_NODES / 256, 256, 0, stream>>>(cnt);
    csr_fill<<<2048, 256, 0, stream>>>(row, col, ew, deg, rowptr, cnt, csr_src, csr_w);

    // layer 1
    gemm64<<<N_NODES / 16, 256, 0, stream>>>(x, W1, hbuf);
    aggregate_csr<<<N_NODES / 4, 256, 0, stream>>>(rowptr, csr_src, csr_w, hbuf, deg, b1, agg);

    // layer 2
    gemm64<<<N_NODES / 16, 256, 0, stream>>>(agg, W2, hbuf);
    aggregate_csr<<<N_NODES / 4, 256, 0, stream>>>(rowptr, csr_src, csr_w, hbuf, deg, b2, agg);

    pool_kernel<<<M_POOL / 4, 256, 0, stream>>>(agg, out);
}

// Round 3
// 288.297 us; speedup vs baseline: 2.0323x; 1.2465x over previous
//
#include <hip/hip_runtime.h>

#define N_NODES 65536
#define N_EDGES 1048576
#define DIM 64
#define M_POOL (N_NODES / DIM)  // 1024

// ---------------- zero in-degree counters ----------------

__global__ __launch_bounds__(256) void zero_cnt(int* __restrict__ cnt) {
    int i = blockIdx.x * 256 + threadIdx.x;
    if (i < N_NODES) cnt[i] = 0;
}

// ---------------- edge pass 1: in-degree histogram + per-edge bucket offset -

__global__ __launch_bounds__(256) void edge_pass1(const int* __restrict__ col,
                                                  int* __restrict__ cnt,
                                                  int* __restrict__ eoff) {
    int e = blockIdx.x * 256 + threadIdx.x;
    int stride = gridDim.x * 256;
    for (; e < N_EDGES; e += stride)
        eoff[e] = atomicAdd(&cnt[col[e]], 1);
}

// ---------------- exclusive scan of cnt[65536] -> rowptr[65537] -------------

__global__ __launch_bounds__(1024) void scan_counts(const int* __restrict__ cnt,
                                                    int* __restrict__ rowptr) {
    __shared__ int part[1024];
    const int t = threadIdx.x;
    const int base = t * 64;
    int s = 0;
    for (int i = 0; i < 64; ++i) s += cnt[base + i];
    part[t] = s;
    __syncthreads();
    for (int off = 1; off < 1024; off <<= 1) {
        int v = (t >= off) ? part[t - off] : 0;
        __syncthreads();
        part[t] += v;
        __syncthreads();
    }
    int offset = (t == 0) ? 0 : part[t - 1];
    for (int i = 0; i < 64; ++i) {
        rowptr[base + i] = offset;
        offset += cnt[base + i];
    }
    if (t == 1023) rowptr[N_NODES] = part[1023];
}

// ---------------- CSR fill — NO atomics, packed int2{src, ew_bits} ----------

__global__ __launch_bounds__(256) void csr_fill(const int* __restrict__ row,
                                                const int* __restrict__ col,
                                                const float* __restrict__ ew,
                                                const int* __restrict__ eoff,
                                                const int* __restrict__ rowptr,
                                                int2* __restrict__ csr) {
    int e = blockIdx.x * 256 + threadIdx.x;
    int stride = gridDim.x * 256;
    for (; e < N_EDGES; e += stride) {
        int c = col[e];
        int idx = rowptr[c] + eoff[e];
        csr[idx] = make_int2(row[e], __float_as_int(ew[e]));
    }
}

// ---------------- dinv from CSR: dinv[c] = 1/sqrt(1 + sum ew) ---------------
// one wave per node, coalesced CSR row read, shuffle reduce

__global__ __launch_bounds__(256) void deg_dinv(const int* __restrict__ rowptr,
                                                const int2* __restrict__ csr,
                                                float* __restrict__ dinv) {
    const int lane = threadIdx.x & 63;
    const int node = (blockIdx.x * 256 + threadIdx.x) >> 6;
    const int start = rowptr[node];
    const int end = rowptr[node + 1];
    float s = 0.f;
    for (int i = start + lane; i < end; i += 64)
        s += __int_as_float(csr[i].y);
#pragma unroll
    for (int off = 32; off > 0; off >>= 1) s += __shfl_down(s, off, 64);
    if (lane == 0) dinv[node] = 1.0f / sqrtf(1.0f + s);
}

// ---------------- GEMM: h = xin @ W ----------------------------------------

__global__ __launch_bounds__(256) void gemm64(const float* __restrict__ xin,
                                              const float* __restrict__ W,
                                              float* __restrict__ h) {
    __shared__ float Ws[DIM * DIM];
    __shared__ float Xs[16][DIM];
    const int tid = threadIdx.x;
    const int row0 = blockIdx.x * 16;

    for (int i = tid; i < DIM * DIM; i += 256) Ws[i] = W[i];
    for (int i = tid; i < 16 * DIM; i += 256)
        Xs[i >> 6][i & 63] = xin[(row0 + (i >> 6)) * DIM + (i & 63)];
    __syncthreads();

    const int j = tid & 63;
    const int rs = tid >> 6;
    for (int rr = 0; rr < 4; ++rr) {
        const int r = rs * 4 + rr;
        float acc = 0.f;
#pragma unroll
        for (int k = 0; k < DIM; ++k) acc += Xs[r][k] * Ws[k * DIM + j];
        h[(row0 + r) * DIM + j] = acc;
    }
}

// ---------------- aggregate: agg[c] = b + dv^2*h[c] + dv*sum(dinv[s]*ew*h[s])

__global__ __launch_bounds__(256) void aggregate_csr(const int* __restrict__ rowptr,
                                                     const int2* __restrict__ csr,
                                                     const float* __restrict__ h,
                                                     const float* __restrict__ dinv,
                                                     const float* __restrict__ b,
                                                     float* __restrict__ agg) {
    const int lane = threadIdx.x & 63;
    const int node = (blockIdx.x * 256 + threadIdx.x) >> 6;  // 4 nodes/block
    const int start = rowptr[node];
    const int end = rowptr[node + 1];
    const float dv = dinv[node];
    float acc = 0.f;

    int i = start;
    for (; i + 3 < end; i += 4) {
        const int2 v0 = csr[i + 0];
        const int2 v1 = csr[i + 1];
        const int2 v2 = csr[i + 2];
        const int2 v3 = csr[i + 3];
        const float w0 = __int_as_float(v0.y) * dinv[v0.x];
        const float w1 = __int_as_float(v1.y) * dinv[v1.x];
        const float w2 = __int_as_float(v2.y) * dinv[v2.x];
        const float w3 = __int_as_float(v3.y) * dinv[v3.x];
        const float h0 = h[v0.x * DIM + lane];
        const float h1 = h[v1.x * DIM + lane];
        const float h2 = h[v2.x * DIM + lane];
        const float h3 = h[v3.x * DIM + lane];
        acc += w0 * h0;
        acc += w1 * h1;
        acc += w2 * h2;
        acc += w3 * h3;
    }
    for (; i < end; ++i) {
        const int2 v = csr[i];
        acc += __int_as_float(v.y) * dinv[v.x] * h[v.x * DIM + lane];
    }

    agg[node * DIM + lane] = acc * dv + h[node * DIM + lane] * dv * dv + b[lane];
}

// ---------------- pooling: out[d][m] = mean_w agg[(m*64+w)][d] --------------

__global__ __launch_bounds__(256) void pool_kernel(const float* __restrict__ agg,
                                                   float* __restrict__ out) {
    const int tid = threadIdx.x;
    const int d = tid & 63;
    const int m = blockIdx.x * 4 + (tid >> 6);
    float acc = 0.f;
#pragma unroll 8
    for (int w = 0; w < DIM; ++w) acc += agg[(m * DIM + w) * DIM + d];
    out[d * M_POOL + m] = acc * (1.0f / DIM);
}

// ---------------- launcher --------------------------------------------------

extern "C" void kernel_launch(void* const* d_in, const int* in_sizes, int n_in,
                              void* d_out, int out_size, void* d_ws, size_t ws_size,
                              hipStream_t stream) {
    const float* x  = (const float*)d_in[0];
    const int*   ei = (const int*)d_in[1];   // [2][E]
    const float* ew = (const float*)d_in[2];
    const float* W1 = (const float*)d_in[3];
    const float* b1 = (const float*)d_in[4];
    const float* W2 = (const float*)d_in[5];
    const float* b2 = (const float*)d_in[6];
    float* out = (float*)d_out;

    char* w = (char*)d_ws;
    int*   cnt    = (int*)w;   w += (size_t)N_NODES * 4;
    int*   rowptr = (int*)w;   w += (size_t)(N_NODES + 16) * 4;
    int2*  csr    = (int2*)w;  w += (size_t)N_EDGES * 8;        // 8 MB
    float* dinv   = (float*)w; w += (size_t)N_NODES * 4;
    float* hbuf   = (float*)w; w += (size_t)N_NODES * DIM * 4;  // 16 MB
    float* agg    = (float*)w;                                   // 16 MB
    int*   eoff   = (int*)agg;  // aliases agg: dead before aggregate1 writes

    const int* row = ei;             // edge_index[0]
    const int* col = ei + N_EDGES;   // edge_index[1]

    // graph preprocessing (shared by both layers)
    zero_cnt<<<N_NODES / 256, 256, 0, stream>>>(cnt);
    edge_pass1<<<2048, 256, 0, stream>>>(col, cnt, eoff);
    scan_counts<<<1, 1024, 0, stream>>>(cnt, rowptr);
    csr_fill<<<2048, 256, 0, stream>>>(row, col, ew, eoff, rowptr, csr);
    deg_dinv<<<N_NODES / 4, 256, 0, stream>>>(rowptr, csr, dinv);

    // layer 1
    gemm64<<<N_NODES / 16, 256, 0, stream>>>(x, W1, hbuf);
    aggregate_csr<<<N_NODES / 4, 256, 0, stream>>>(rowptr, csr, hbuf, dinv, b1, agg);

    // layer 2
    gemm64<<<N_NODES / 16, 256, 0, stream>>>(agg, W2, hbuf);
    aggregate_csr<<<N_NODES / 4, 256, 0, stream>>>(rowptr, csr, hbuf, dinv, b2, agg);

    pool_kernel<<<M_POOL / 4, 256, 0, stream>>>(agg, out);
}

// Round 4
// 253.354 us; speedup vs baseline: 2.3126x; 1.1379x over previous
//
#include <hip/hip_runtime.h>

#define N_NODES 65536
#define N_EDGES 1048576
#define DIM 64
#define M_POOL (N_NODES / DIM)  // 1024

// ---------------- zero in-degree counters ----------------

__global__ __launch_bounds__(256) void zero_cnt(int* __restrict__ cnt) {
    int i = blockIdx.x * 256 + threadIdx.x;
    if (i < N_NODES) cnt[i] = 0;
}

// ---------------- edge pass 1: in-degree histogram + per-edge bucket offset -

__global__ __launch_bounds__(256) void edge_pass1(const int* __restrict__ col,
                                                  int* __restrict__ cnt,
                                                  int* __restrict__ eoff) {
    int e = blockIdx.x * 256 + threadIdx.x;
    int stride = gridDim.x * 256;
    for (; e < N_EDGES; e += stride)
        eoff[e] = atomicAdd(&cnt[col[e]], 1);
}

// ---------------- exclusive scan of cnt[65536] -> rowptr[65537] -------------

__global__ __launch_bounds__(1024) void scan_counts(const int* __restrict__ cnt,
                                                    int* __restrict__ rowptr) {
    __shared__ int part[1024];
    const int t = threadIdx.x;
    const int base = t * 64;
    int s = 0;
    for (int i = 0; i < 64; ++i) s += cnt[base + i];
    part[t] = s;
    __syncthreads();
    for (int off = 1; off < 1024; off <<= 1) {
        int v = (t >= off) ? part[t - off] : 0;
        __syncthreads();
        part[t] += v;
        __syncthreads();
    }
    int offset = (t == 0) ? 0 : part[t - 1];
    for (int i = 0; i < 64; ++i) {
        rowptr[base + i] = offset;
        offset += cnt[base + i];
    }
    if (t == 1023) rowptr[N_NODES] = part[1023];
}

// ---------------- CSR fill — NO atomics, packed int2{src, ew_bits} ----------

__global__ __launch_bounds__(256) void csr_fill(const int* __restrict__ row,
                                                const int* __restrict__ col,
                                                const float* __restrict__ ew,
                                                const int* __restrict__ eoff,
                                                const int* __restrict__ rowptr,
                                                int2* __restrict__ csr) {
    int e = blockIdx.x * 256 + threadIdx.x;
    int stride = gridDim.x * 256;
    for (; e < N_EDGES; e += stride) {
        int c = col[e];
        int idx = rowptr[c] + eoff[e];
        csr[idx] = make_int2(row[e], __float_as_int(ew[e]));
    }
}

// ---------------- dinv from CSR: dinv[c] = 1/sqrt(1 + sum ew) ---------------

__global__ __launch_bounds__(256) void deg_dinv(const int* __restrict__ rowptr,
                                                const int2* __restrict__ csr,
                                                float* __restrict__ dinv) {
    const int lane = threadIdx.x & 63;
    const int node = (blockIdx.x * 256 + threadIdx.x) >> 6;
    const int start = rowptr[node];
    const int end = rowptr[node + 1];
    float s = 0.f;
    for (int i = start + lane; i < end; i += 64)
        s += __int_as_float(csr[i].y);
#pragma unroll
    for (int off = 32; off > 0; off >>= 1) s += __shfl_down(s, off, 64);
    if (lane == 0) dinv[node] = 1.0f / sqrtf(1.0f + s);
}

// ---------------- GEMM: h = xin @ W ----------------------------------------

__global__ __launch_bounds__(256) void gemm64(const float* __restrict__ xin,
                                              const float* __restrict__ W,
                                              float* __restrict__ h) {
    __shared__ float Ws[DIM * DIM];
    __shared__ float Xs[16][DIM];
    const int tid = threadIdx.x;
    const int row0 = blockIdx.x * 16;

    for (int i = tid; i < DIM * DIM; i += 256) Ws[i] = W[i];
    for (int i = tid; i < 16 * DIM; i += 256)
        Xs[i >> 6][i & 63] = xin[(row0 + (i >> 6)) * DIM + (i & 63)];
    __syncthreads();

    const int j = tid & 63;
    const int rs = tid >> 6;
    for (int rr = 0; rr < 4; ++rr) {
        const int r = rs * 4 + rr;
        float acc = 0.f;
#pragma unroll
        for (int k = 0; k < DIM; ++k) acc += Xs[r][k] * Ws[k * DIM + j];
        h[(row0 + r) * DIM + j] = acc;
    }
}

// ---------------- aggregate layer 1 -----------------------------------------
// wave = 1 node; 4 groups x 16 lanes; each lane reads float4 -> 4 edge-rows
// per load instruction, 8 in flight with unroll 2.
// out[n] = sum(norm * h[src]) + dv^2 * h[n] + b ; also csr.y <- full norm.

__global__ __launch_bounds__(256) void aggregate_l1(const int* __restrict__ rowptr,
                                                    int2* __restrict__ csr,
                                                    const float* __restrict__ h,
                                                    const float* __restrict__ dinv,
                                                    const float* __restrict__ b,
                                                    float* __restrict__ out) {
    const int lane = threadIdx.x & 63;
    const int node = (blockIdx.x * 256 + threadIdx.x) >> 6;
    const int g = lane >> 4;   // edge subgroup 0..3
    const int q = lane & 15;   // dim quad: dims q*4..q*4+3
    const int start = rowptr[node];
    const int end = rowptr[node + 1];
    const float dv = dinv[node];

    float4 acc = make_float4(0.f, 0.f, 0.f, 0.f);
    for (int i = start; i < end; i += 8) {
        const int i0 = i + g;
        const int i1 = i + 4 + g;
        const int2 v0 = (i0 < end) ? csr[i0] : make_int2(0, 0);
        const int2 v1 = (i1 < end) ? csr[i1] : make_int2(0, 0);
        const float w0 = __int_as_float(v0.y) * dinv[v0.x] * dv;
        const float w1 = __int_as_float(v1.y) * dinv[v1.x] * dv;
        if (q == 0) {  // cache full norm for layer 2
            if (i0 < end) csr[i0].y = __float_as_int(w0);
            if (i1 < end) csr[i1].y = __float_as_int(w1);
        }
        const float4 h0 = *(const float4*)&h[(size_t)v0.x * DIM + q * 4];
        const float4 h1 = *(const float4*)&h[(size_t)v1.x * DIM + q * 4];
        acc.x += w0 * h0.x + w1 * h1.x;
        acc.y += w0 * h0.y + w1 * h1.y;
        acc.z += w0 * h0.z + w1 * h1.z;
        acc.w += w0 * h0.w + w1 * h1.w;
    }
    // combine the 4 edge-subgroups (lanes ^16, ^32)
#pragma unroll
    for (int m = 16; m <= 32; m <<= 1) {
        acc.x += __shfl_xor(acc.x, m, 64);
        acc.y += __shfl_xor(acc.y, m, 64);
        acc.z += __shfl_xor(acc.z, m, 64);
        acc.w += __shfl_xor(acc.w, m, 64);
    }
    const float4 hs = *(const float4*)&h[(size_t)node * DIM + q * 4];
    const float4 bb = *(const float4*)&b[q * 4];
    float4 r;
    r.x = acc.x + dv * dv * hs.x + bb.x;
    r.y = acc.y + dv * dv * hs.y + bb.y;
    r.z = acc.z + dv * dv * hs.z + bb.z;
    r.w = acc.w + dv * dv * hs.w + bb.w;
    if (lane < 16) *(float4*)&out[(size_t)node * DIM + lane * 4] = r;
}

// ---------------- aggregate layer 2 (csr.y already = full norm; no bias) ----
// g[n] = sum(norm * h1[src]) + dv^2 * h1[n]

__global__ __launch_bounds__(256) void aggregate_l2(const int* __restrict__ rowptr,
                                                    const int2* __restrict__ csr,
                                                    const float* __restrict__ h,
                                                    const float* __restrict__ dinv,
                                                    float* __restrict__ out) {
    const int lane = threadIdx.x & 63;
    const int node = (blockIdx.x * 256 + threadIdx.x) >> 6;
    const int g = lane >> 4;
    const int q = lane & 15;
    const int start = rowptr[node];
    const int end = rowptr[node + 1];

    float4 acc = make_float4(0.f, 0.f, 0.f, 0.f);
    for (int i = start; i < end; i += 8) {
        const int i0 = i + g;
        const int i1 = i + 4 + g;
        const int2 v0 = (i0 < end) ? csr[i0] : make_int2(0, 0);
        const int2 v1 = (i1 < end) ? csr[i1] : make_int2(0, 0);
        const float w0 = __int_as_float(v0.y);
        const float w1 = __int_as_float(v1.y);
        const float4 h0 = *(const float4*)&h[(size_t)v0.x * DIM + q * 4];
        const float4 h1 = *(const float4*)&h[(size_t)v1.x * DIM + q * 4];
        acc.x += w0 * h0.x + w1 * h1.x;
        acc.y += w0 * h0.y + w1 * h1.y;
        acc.z += w0 * h0.z + w1 * h1.z;
        acc.w += w0 * h0.w + w1 * h1.w;
    }
#pragma unroll
    for (int m = 16; m <= 32; m <<= 1) {
        acc.x += __shfl_xor(acc.x, m, 64);
        acc.y += __shfl_xor(acc.y, m, 64);
        acc.z += __shfl_xor(acc.z, m, 64);
        acc.w += __shfl_xor(acc.w, m, 64);
    }
    const float dv = dinv[node];
    const float4 hs = *(const float4*)&h[(size_t)node * DIM + q * 4];
    float4 r;
    r.x = acc.x + dv * dv * hs.x;
    r.y = acc.y + dv * dv * hs.y;
    r.z = acc.z + dv * dv * hs.z;
    r.w = acc.w + dv * dv * hs.w;
    if (lane < 16) *(float4*)&out[(size_t)node * DIM + lane * 4] = r;
}

// ---------------- fused pool + layer-2 GEMM ---------------------------------
// out[j][m] = (mean_w g[m*64+w][:]) @ W2[:,j] + b2[j]

__global__ __launch_bounds__(256) void pool_gemm(const float* __restrict__ g,
                                                 const float* __restrict__ W2,
                                                 const float* __restrict__ b2,
                                                 float* __restrict__ out) {
    __shared__ float Ws[DIM * DIM];
    __shared__ float pooled[4][DIM];
    const int t = threadIdx.x;
    for (int i = t; i < DIM * DIM; i += 256) Ws[i] = W2[i];
    const int wi = t >> 6;
    const int d = t & 63;
    const int m = blockIdx.x * 4 + wi;
    float s = 0.f;
#pragma unroll 8
    for (int w = 0; w < DIM; ++w) s += g[((size_t)m * DIM + w) * DIM + d];
    pooled[wi][d] = s * (1.0f / DIM);
    __syncthreads();
    float acc = b2[d];
#pragma unroll
    for (int k = 0; k < DIM; ++k) acc += pooled[wi][k] * Ws[k * DIM + d];
    out[(size_t)d * M_POOL + m] = acc;
}

// ---------------- launcher --------------------------------------------------

extern "C" void kernel_launch(void* const* d_in, const int* in_sizes, int n_in,
                              void* d_out, int out_size, void* d_ws, size_t ws_size,
                              hipStream_t stream) {
    const float* x  = (const float*)d_in[0];
    const int*   ei = (const int*)d_in[1];   // [2][E]
    const float* ew = (const float*)d_in[2];
    const float* W1 = (const float*)d_in[3];
    const float* b1 = (const float*)d_in[4];
    const float* W2 = (const float*)d_in[5];
    const float* b2 = (const float*)d_in[6];
    float* out = (float*)d_out;

    char* w = (char*)d_ws;
    int*   cnt    = (int*)w;   w += (size_t)N_NODES * 4;
    int*   rowptr = (int*)w;   w += (size_t)(N_NODES + 16) * 4;
    int2*  csr    = (int2*)w;  w += (size_t)N_EDGES * 8;        // 8 MB
    float* dinv   = (float*)w; w += (size_t)N_NODES * 4;
    float* buf1   = (float*)w; w += (size_t)N_NODES * DIM * 4;  // 16 MB
    float* buf2   = (float*)w;                                   // 16 MB
    int*   eoff   = (int*)buf2;  // dead after csr_fill, before buf2 written

    const int* row = ei;             // edge_index[0]
    const int* col = ei + N_EDGES;   // edge_index[1]

    // graph preprocessing (shared by both layers)
    zero_cnt<<<N_NODES / 256, 256, 0, stream>>>(cnt);
    edge_pass1<<<2048, 256, 0, stream>>>(col, cnt, eoff);
    scan_counts<<<1, 1024, 0, stream>>>(cnt, rowptr);
    csr_fill<<<2048, 256, 0, stream>>>(row, col, ew, eoff, rowptr, csr);
    deg_dinv<<<N_NODES / 4, 256, 0, stream>>>(rowptr, csr, dinv);

    // layer 1: h' = x@W1 ; h1 = A h' + b1   (also caches norm into csr.y)
    gemm64<<<N_NODES / 16, 256, 0, stream>>>(x, W1, buf1);
    aggregate_l1<<<N_NODES / 4, 256, 0, stream>>>(rowptr, csr, buf1, dinv, b1, buf2);

    // layer 2 (algebraically reordered): g = A h1 ; out = pool(g)@W2 + b2
    aggregate_l2<<<N_NODES / 4, 256, 0, stream>>>(rowptr, csr, buf2, dinv, buf1);
    pool_gemm<<<M_POOL / 4, 256, 0, stream>>>(buf1, W2, b2, out);
}